// Round 1
// baseline (63.642 us; speedup 1.0000x reference)
//
#include <hip/hip_runtime.h>

#define Bn 512

// sigmoid((sk - sj)/tau) = 1 / (1 + exp((sj - sk)/tau)) = 1 / (1 + exp2(tj - tk))
// where t = s * log2(e)/tau.
__device__ __forceinline__ float sigterm(float tj, float tk) {
    float e = __builtin_amdgcn_exp2f(tj - tk);
    return __builtin_amdgcn_rcpf(1.0f + e);
}

__global__ __launch_bounds__(512, 2) void srap_main(
        const float* __restrict__ scores,
        const float* __restrict__ target,
        float* __restrict__ ap) {
    __shared__ __align__(16) float t[Bn];
    __shared__ float cs[8], ts[8];

    const int b = blockIdx.x;
    const int j = threadIdx.x;

    const float C = 144.26950408889634f;  // log2(e) / tau, tau = 0.01
    t[j] = scores[(size_t)b * Bn + j] * C;
    __syncthreads();

    const float tj = t[j];
    const float4* __restrict__ trow = (const float4*)(target + (size_t)j * Bn);

    float A = 0.0f;  // sum_k sigmoid
    float P = 0.0f;  // sum_k sigmoid * target[j,k]

#pragma unroll 4
    for (int k4 = 0; k4 < Bn / 4; ++k4) {
        const float4 p  = trow[k4];                       // target[j, 4k..4k+3]
        const float4 tk = *(const float4*)(&t[k4 * 4]);   // uniform LDS broadcast

        float s0 = sigterm(tj, tk.x);
        float s1 = sigterm(tj, tk.y);
        float s2 = sigterm(tj, tk.z);
        float s3 = sigterm(tj, tk.w);

        A += (s0 + s1) + (s2 + s3);
        P = fmaf(s0, p.x, P);
        P = fmaf(s1, p.y, P);
        P = fmaf(s2, p.z, P);
        P = fmaf(s3, p.w, P);
    }

    // sim_all_rk = (A - 0.5 [diag sig]) + 1.0 [self] = A + 0.5
    // pos sum    = (P - 0.5 [diag: sig(0)*target[j,j] = 0.5*1])
    // sim_pos_rk = (pos + target[b,j]) * target[b,j]
    const float A_all = A + 0.5f;
    const float tbj   = target[(size_t)b * Bn + j];
    const float Ppos  = P - 0.5f + tbj;
    float c = (Ppos * tbj) / A_all;   // per-j contribution to ap numerator
    float tt = tbj;                    // contribution to sum_j target[b,j]

    // block reduction (8 waves of 64)
    for (int off = 32; off; off >>= 1) {
        c  += __shfl_down(c, off);
        tt += __shfl_down(tt, off);
    }
    const int wave = threadIdx.x >> 6;
    const int lane = threadIdx.x & 63;
    if (lane == 0) { cs[wave] = c; ts[wave] = tt; }
    __syncthreads();
    if (threadIdx.x == 0) {
        float csum = 0.0f, tsum = 0.0f;
#pragma unroll
        for (int w = 0; w < 8; ++w) { csum += cs[w]; tsum += ts[w]; }
        ap[b] = csum / tsum;
    }
}

__global__ void srap_final(const float* __restrict__ ap, float* __restrict__ out) {
    const int lane = threadIdx.x;  // 64 threads
    float s = 0.0f;
#pragma unroll
    for (int i = 0; i < Bn / 64; ++i) s += ap[lane + i * 64];
    for (int off = 32; off; off >>= 1) s += __shfl_down(s, off);
    if (lane == 0) out[0] = 1.0f - s * (1.0f / Bn);
}

extern "C" void kernel_launch(void* const* d_in, const int* in_sizes, int n_in,
                              void* d_out, int out_size, void* d_ws, size_t ws_size,
                              hipStream_t stream) {
    const float* scores = (const float*)d_in[0];
    const float* target = (const float*)d_in[1];
    float* out = (float*)d_out;
    float* ap  = (float*)d_ws;   // 512 floats

    srap_main<<<dim3(Bn), dim3(Bn), 0, stream>>>(scores, target, ap);
    srap_final<<<dim3(1), dim3(64), 0, stream>>>(ap, out);
}